// Round 7
// baseline (842.708 us; speedup 1.0000x reference)
//
#include <hip/hip_runtime.h>

typedef unsigned short u16;
typedef unsigned int u32;
using f32x4 = __attribute__((ext_vector_type(4))) float;
using u32x4 = __attribute__((ext_vector_type(4))) u32;
typedef u32x4 __attribute__((may_alias)) u32x4a;  // TBAA-safe 16B vector
using bf16x8 = __attribute__((ext_vector_type(8))) __bf16;

#define SEQ 2048  // per batch

// fp32 -> bf16 round-to-nearest-even
__device__ __forceinline__ u16 f2bf(float f) {
  union { float f; u32 u; } c; c.f = f;
  return (u16)((c.u + 0x7fffu + ((c.u >> 16) & 1u)) >> 16);
}
__device__ __forceinline__ float bf2f(u16 h) {
  union { u32 u; float f; } c; c.u = ((u32)h) << 16;
  return c.f;
}
__device__ __forceinline__ bf16x8 ld16(const u16* p) {
  return __builtin_bit_cast(bf16x8, *(const u32x4a*)p);
}
__device__ __forceinline__ f32x4 mfma16(bf16x8 a, bf16x8 b, f32x4 c) {
  return __builtin_amdgcn_mfma_f32_16x16x32_bf16(a, b, c, 0, 0, 0);
}

// ---------------- input dtype detection ----------------
// bf16 N(0,1): u16 exponent field in [100,140] (~always). fp32: even u16s are
// mantissa low bits (uniform) -> E[cnt]=5 of 32. Threshold 20 separates >7σ.
__global__ void detect_dtype(const u16* __restrict__ x, int* __restrict__ flag) {
  if (threadIdx.x == 0) {
    int cnt = 0;
    for (int i = 0; i < 32; ++i) {
      const int e = (x[2 * i] >> 7) & 0xFF;
      cnt += (e >= 100 && e <= 140) ? 1 : 0;
    }
    *flag = (cnt >= 20) ? 1 : 0;  // 1 = inputs are bf16
  }
}

// ---------------- prep kernels ----------------

// x (fp32 or bf16) slice -> bf16. 4 elems/thread.
__global__ __launch_bounds__(256)
void cvt_x(const void* __restrict__ in, u16* __restrict__ out,
           const int* __restrict__ flag, size_t eoff4) {
  const size_t i = (size_t)blockIdx.x * 256 + threadIdx.x;
  if (*flag) {
    ((uint2*)out)[i] = ((const uint2*)in)[eoff4 + i];
  } else {
    const float4 v = ((const float4*)in)[eoff4 + i];
    uint2 ov;
    ov.x = (u32)f2bf(v.x) | ((u32)f2bf(v.y) << 16);
    ov.y = (u32)f2bf(v.z) | ((u32)f2bf(v.w) << 16);
    ((uint2*)out)[i] = ov;
  }
}

// bias (fp32 or bf16) -> fp32
__global__ __launch_bounds__(256)
void cvt_bias(const void* __restrict__ in, float* __restrict__ out, int n,
              const int* __restrict__ flag) {
  const int i = blockIdx.x * 256 + threadIdx.x;
  if (i >= n) return;
  out[i] = (*flag) ? bf2f(((const u16*)in)[i]) : ((const float*)in)[i];
}

// in [K,N] (fp32 or bf16) -> out bf16 [N,K]. 64x64 tiles via LDS.
__global__ __launch_bounds__(256)
void transpose_w(const void* __restrict__ in, u16* __restrict__ out, int K, int N,
                 const int* __restrict__ flag) {
  __shared__ float t[64][65];
  const int tid = threadIdx.x;
  const int r = tid >> 4, c4 = tid & 15;
  const int n0 = blockIdx.x << 6, k0 = blockIdx.y << 6;
  const int fl = *flag;
#pragma unroll
  for (int i = 0; i < 4; ++i) {
    const int kk = r + i * 16;
    const size_t base = (size_t)(k0 + kk) * N + n0 + c4 * 4;
    if (fl) {
      const uint2 raw = *(const uint2*)((const u16*)in + base);
      t[kk][c4 * 4 + 0] = bf2f((u16)(raw.x & 0xFFFF));
      t[kk][c4 * 4 + 1] = bf2f((u16)(raw.x >> 16));
      t[kk][c4 * 4 + 2] = bf2f((u16)(raw.y & 0xFFFF));
      t[kk][c4 * 4 + 3] = bf2f((u16)(raw.y >> 16));
    } else {
      const float4 v = *(const float4*)((const float*)in + base);
      t[kk][c4 * 4 + 0] = v.x; t[kk][c4 * 4 + 1] = v.y;
      t[kk][c4 * 4 + 2] = v.z; t[kk][c4 * 4 + 3] = v.w;
    }
  }
  __syncthreads();
#pragma unroll
  for (int i = 0; i < 4; ++i) {
    const int nn = r + i * 16;
    uint2 ov;
    ov.x = (u32)f2bf(t[c4 * 4 + 0][nn]) | ((u32)f2bf(t[c4 * 4 + 1][nn]) << 16);
    ov.y = (u32)f2bf(t[c4 * 4 + 2][nn]) | ((u32)f2bf(t[c4 * 4 + 3][nn]) << 16);
    *(uint2*)&out[(size_t)(n0 + nn) * K + k0 + c4 * 4] = ov;
  }
}

// per-batch: qkvb bf16 [2048,3072] (V cols 2048..3071) -> vtb [h=16][d=64][s=2048]
// (full 16-element staging per thread — the R4 fix)
__global__ __launch_bounds__(256)
void transpose_v(const u16* __restrict__ qkvb, u16* __restrict__ vtb) {
  __shared__ __align__(16) u16 t[64][72];
  const int h = blockIdx.x, s0 = blockIdx.y << 6;
  const int tid = threadIdx.x;
  const int r = tid >> 2, g = tid & 3;
  const u16* src = &qkvb[(size_t)(s0 + r) * 3072 + 2048 + h * 64 + g * 16];
  *(u32x4a*)&t[r][g * 16]     = *(const u32x4a*)src;
  *(u32x4a*)&t[r][g * 16 + 8] = *(const u32x4a*)(src + 8);
  __syncthreads();
  union { u16 s[16]; u32x4 v[2]; } u;
#pragma unroll
  for (int e = 0; e < 16; ++e) u.s[e] = t[g * 16 + e][r];
  u16* dst = &vtb[(size_t)(h * 64 + r) * 2048 + s0 + g * 16];
  *(u32x4a*)dst = u.v[0];
  *(u32x4a*)(dst + 8) = u.v[1];
}

// ---------------- GEMM: C[M,N] = A[M,K]*BT[N,K]^T + bias ----------------
// 128x128 tile, BK=32, 4 waves 2x2. Output dtype templated:
// BF16_OUT=true -> u16 bf16 store (intermediate), false -> fp32 store (d_out).
template <bool BF16_OUT>
__global__ __launch_bounds__(256)
void gemm_bt(const u16* __restrict__ A, const u16* __restrict__ BT,
             const float* __restrict__ bias, void* __restrict__ Cv,
             int M, int N, int K) {
  constexpr int BK = 32, LDW = 40;
  __shared__ __align__(16) u16 lA[128 * LDW];
  __shared__ __align__(16) u16 lB[128 * LDW];
  const int tid = threadIdx.x;
  const int wid = tid >> 6, lane = tid & 63;
  const int quad = lane >> 4, l16 = lane & 15;
  const int tile_m = blockIdx.y << 7, tile_n = blockIdx.x << 7;
  const int wm = (wid >> 1) << 6, wn = (wid & 1) << 6;
  const int srow0 = tid >> 2, kc = (tid & 3) * 8;  // stage rows srow0, srow0+64

  f32x4 acc[4][4] = {};

  for (int k0 = 0; k0 < K; k0 += BK) {
    u32x4 va[2], vb[2];
#pragma unroll
    for (int c = 0; c < 2; ++c) {
      const int row = srow0 + c * 64;
      va[c] = *(const u32x4a*)&A[(size_t)(tile_m + row) * K + k0 + kc];
      vb[c] = *(const u32x4a*)&BT[(size_t)(tile_n + row) * K + k0 + kc];
    }
    __syncthreads();  // previous iteration's reads done before overwrite
#pragma unroll
    for (int c = 0; c < 2; ++c) {
      const int row = srow0 + c * 64;
      *(u32x4a*)&lA[row * LDW + kc] = va[c];
      *(u32x4a*)&lB[row * LDW + kc] = vb[c];
    }
    __syncthreads();
    bf16x8 af[4], bfr[4];
#pragma unroll
    for (int i = 0; i < 4; ++i) {
      af[i]  = ld16(&lA[(wm + i * 16 + l16) * LDW + quad * 8]);
      bfr[i] = ld16(&lB[(wn + i * 16 + l16) * LDW + quad * 8]);
    }
#pragma unroll
    for (int i = 0; i < 4; ++i)
#pragma unroll
      for (int j = 0; j < 4; ++j) acc[i][j] = mfma16(af[i], bfr[j], acc[i][j]);
  }

#pragma unroll
  for (int j = 0; j < 4; ++j) {
    const int cg = tile_n + wn + j * 16 + l16;
    const float bv = bias[cg];
#pragma unroll
    for (int i = 0; i < 4; ++i) {
      const int rg = tile_m + wm + i * 16 + quad * 4;
#pragma unroll
      for (int r = 0; r < 4; ++r) {
        const float v = acc[i][j][r] + bv;
        if constexpr (BF16_OUT)
          ((u16*)Cv)[(size_t)(rg + r) * N + cg] = f2bf(v);
        else
          ((float*)Cv)[(size_t)(rg + r) * N + cg] = v;  // d_out is fp32!
      }
    }
  }
}

// ---------------- causal flash attention (per batch) ----------------
// block = (h, qtile of 64); wave w owns q rows qtile*64+w*16..+15.
// Validated vs naive VALU attention (R4 == R5 output).
__global__ __launch_bounds__(256)
void attn_fwd(const u16* __restrict__ qkvb, const u16* __restrict__ vtb,
              u16* __restrict__ aout) {
  const int h = blockIdx.x, qt = blockIdx.y;
  const int tid = threadIdx.x, wid = tid >> 6, lane = tid & 63;
  const int quad = lane >> 4, l16 = lane & 15;
  const int q0 = qt * 64 + wid * 16;
  __shared__ __align__(16) u16 lP[4][16][72];  // per-wave, 144B row stride

  bf16x8 aq0, aq1;
  {
    const size_t qi = (size_t)(q0 + l16) * 3072 + h * 64 + quad * 8;
    aq0 = ld16(&qkvb[qi]);
    aq1 = ld16(&qkvb[qi + 32]);
  }
  const f32x4 z = {0.f, 0.f, 0.f, 0.f};
  f32x4 o[4] = {z, z, z, z};
  float m_r[4] = {-1e30f, -1e30f, -1e30f, -1e30f};
  float l_r[4] = {0.f, 0.f, 0.f, 0.f};

  for (int kt = 0; kt <= qt; ++kt) {  // qt uniform per block: barriers legal
    const int kbase = kt * 64;
    f32x4 s[4];
#pragma unroll
    for (int f = 0; f < 4; ++f) {
      const size_t ki =
          (size_t)(kbase + f * 16 + l16) * 3072 + 1024 + h * 64 + quad * 8;
      f32x4 a = z;
      a = mfma16(aq0, ld16(&qkvb[ki]), a);
      a = mfma16(aq1, ld16(&qkvb[ki + 32]), a);
      s[f] = a * 0.125f;  // 1/sqrt(64)
    }
    if (kt == qt) {  // diagonal: mask k_local > q_local
#pragma unroll
      for (int f = 0; f < 4; ++f)
#pragma unroll
        for (int r = 0; r < 4; ++r)
          if (f * 16 + l16 > wid * 16 + quad * 4 + r) s[f][r] = -1e30f;
    }
    float alpha[4];
#pragma unroll
    for (int r = 0; r < 4; ++r) {
      float mv = fmaxf(fmaxf(s[0][r], s[1][r]), fmaxf(s[2][r], s[3][r]));
      mv = fmaxf(mv, __shfl_xor(mv, 1));
      mv = fmaxf(mv, __shfl_xor(mv, 2));
      mv = fmaxf(mv, __shfl_xor(mv, 4));
      mv = fmaxf(mv, __shfl_xor(mv, 8));
      const float mn = fmaxf(m_r[r], mv);
      alpha[r] = __expf(m_r[r] - mn);
      m_r[r] = mn;
    }
    f32x4 p[4];
#pragma unroll
    for (int f = 0; f < 4; ++f)
#pragma unroll
      for (int r = 0; r < 4; ++r) p[f][r] = __expf(s[f][r] - m_r[r]);
#pragma unroll
    for (int r = 0; r < 4; ++r) {
      float sv = p[0][r] + p[1][r] + p[2][r] + p[3][r];
      sv += __shfl_xor(sv, 1);
      sv += __shfl_xor(sv, 2);
      sv += __shfl_xor(sv, 4);
      sv += __shfl_xor(sv, 8);
      l_r[r] = l_r[r] * alpha[r] + sv;
    }
#pragma unroll
    for (int f = 0; f < 4; ++f)
#pragma unroll
      for (int r = 0; r < 4; ++r) {
        o[f][r] *= alpha[r];
        lP[wid][quad * 4 + r][f * 16 + l16] = f2bf(p[f][r]);
      }
    __syncthreads();  // fence P writes -> reads
    const bf16x8 ap0 = ld16(&lP[wid][l16][quad * 8]);
    const bf16x8 ap1 = ld16(&lP[wid][l16][quad * 8 + 32]);
#pragma unroll
    for (int f = 0; f < 4; ++f) {
      const size_t vi = (size_t)(h * 64 + f * 16 + l16) * 2048 + kbase + quad * 8;
      o[f] = mfma16(ap0, ld16(&vtb[vi]), o[f]);
      o[f] = mfma16(ap1, ld16(&vtb[vi + 32]), o[f]);
    }
    __syncthreads();  // P consumed before next iteration overwrites
  }
  float inv[4];
#pragma unroll
  for (int r = 0; r < 4; ++r) inv[r] = 1.0f / l_r[r];
#pragma unroll
  for (int f = 0; f < 4; ++f)
#pragma unroll
    for (int r = 0; r < 4; ++r)
      aout[(size_t)(q0 + quad * 4 + r) * 1024 + h * 64 + f * 16 + l16] =
          f2bf(o[f][r] * inv[r]);
}

extern "C" void kernel_launch(void* const* d_in, const int* in_sizes, int n_in,
                              void* d_out, int out_size, void* d_ws, size_t ws_size,
                              hipStream_t stream) {
  const void* x     = d_in[0];
  const void* w_qkv = d_in[1];
  const void* b_qkv = d_in[2];
  const void* w_out = d_in[3];
  const void* b_out = d_in[4];
  // Reference output dtype is float32 -> d_out is fp32 (harness contract).
  float* out = (float*)d_out;

  // workspace: 29.4 MB total (batch-chunked)
  float* bqf   = (float*)d_ws;                      // [3072] fp32
  float* bof   = bqf + 3072;                        // [1024] fp32
  int*   flag  = (int*)(bof + 1024);                // [4]
  u16*   wqkvT = (u16*)(flag + 4);                  // [3072,1024]
  u16*   woutT = wqkvT + (size_t)3072 * 1024;       // [1024,1024]
  u16*   xb    = woutT + (size_t)1024 * 1024;       // [2048,1024] per-batch
  u16*   qkvb  = xb    + (size_t)2048 * 1024;       // [2048,3072] per-batch
  u16*   vtb   = qkvb  + (size_t)2048 * 3072;       // [16,64,2048] per-batch

  detect_dtype<<<dim3(1), dim3(64), 0, stream>>>((const u16*)x, flag);
  cvt_bias<<<dim3(12), dim3(256), 0, stream>>>(b_qkv, bqf, 3072, flag);
  cvt_bias<<<dim3(4), dim3(256), 0, stream>>>(b_out, bof, 1024, flag);
  transpose_w<<<dim3(48, 16), dim3(256), 0, stream>>>(w_qkv, wqkvT, 1024, 3072, flag);
  transpose_w<<<dim3(16, 16), dim3(256), 0, stream>>>(w_out, woutT, 1024, 1024, flag);

  for (int b = 0; b < 4; ++b) {
    const size_t eoff4 = (size_t)b * 2048 * 1024 / 4;
    cvt_x<<<dim3(2048), dim3(256), 0, stream>>>(x, xb, flag, eoff4);
    gemm_bt<true ><<<dim3(24, 16), dim3(256), 0, stream>>>(xb, wqkvT, bqf, qkvb,
                                                           2048, 3072, 1024);
    transpose_v<<<dim3(16, 32), dim3(256), 0, stream>>>(qkvb, vtb);
    attn_fwd<<<dim3(16, 32), dim3(256), 0, stream>>>(qkvb, vtb, xb);  // xb = attn out
    gemm_bt<false><<<dim3(8, 16), dim3(256), 0, stream>>>(
        xb, woutT, bof, out + (size_t)b * 2048 * 1024, 2048, 1024, 1024);
  }
}

// Round 8
// 590.788 us; speedup vs baseline: 1.4264x; 1.4264x over previous
//
#include <hip/hip_runtime.h>

typedef unsigned short u16;
typedef unsigned int u32;
using f32x4 = __attribute__((ext_vector_type(4))) float;
using u32x4 = __attribute__((ext_vector_type(4))) u32;
typedef u32x4 __attribute__((may_alias)) u32x4a;  // TBAA-safe 16B vector
using bf16x8 = __attribute__((ext_vector_type(8))) __bf16;

#define SEQ 2048  // per batch

// fp32 -> bf16 round-to-nearest-even
__device__ __forceinline__ u16 f2bf(float f) {
  union { float f; u32 u; } c; c.f = f;
  return (u16)((c.u + 0x7fffu + ((c.u >> 16) & 1u)) >> 16);
}
__device__ __forceinline__ float bf2f(u16 h) {
  union { u32 u; float f; } c; c.u = ((u32)h) << 16;
  return c.f;
}
__device__ __forceinline__ bf16x8 ld16(const u16* p) {
  return __builtin_bit_cast(bf16x8, *(const u32x4a*)p);
}
__device__ __forceinline__ f32x4 mfma16(bf16x8 a, bf16x8 b, f32x4 c) {
  return __builtin_amdgcn_mfma_f32_16x16x32_bf16(a, b, c, 0, 0, 0);
}

// ---------------- input dtype detection ----------------
__global__ void detect_dtype(const u16* __restrict__ x, int* __restrict__ flag) {
  if (threadIdx.x == 0) {
    int cnt = 0;
    for (int i = 0; i < 32; ++i) {
      const int e = (x[2 * i] >> 7) & 0xFF;
      cnt += (e >= 100 && e <= 140) ? 1 : 0;
    }
    *flag = (cnt >= 20) ? 1 : 0;  // 1 = inputs are bf16
  }
}

// ---------------- prep kernels ----------------

// x (fp32 or bf16) slice -> bf16. 4 elems/thread.
__global__ __launch_bounds__(256)
void cvt_x(const void* __restrict__ in, u16* __restrict__ out,
           const int* __restrict__ flag, size_t eoff4) {
  const size_t i = (size_t)blockIdx.x * 256 + threadIdx.x;
  if (*flag) {
    ((uint2*)out)[i] = ((const uint2*)in)[eoff4 + i];
  } else {
    const float4 v = ((const float4*)in)[eoff4 + i];
    uint2 ov;
    ov.x = (u32)f2bf(v.x) | ((u32)f2bf(v.y) << 16);
    ov.y = (u32)f2bf(v.z) | ((u32)f2bf(v.w) << 16);
    ((uint2*)out)[i] = ov;
  }
}

// bias (fp32 or bf16) -> fp32
__global__ __launch_bounds__(256)
void cvt_bias(const void* __restrict__ in, float* __restrict__ out, int n,
              const int* __restrict__ flag) {
  const int i = blockIdx.x * 256 + threadIdx.x;
  if (i >= n) return;
  out[i] = (*flag) ? bf2f(((const u16*)in)[i]) : ((const float*)in)[i];
}

// in [K,N] (fp32 or bf16) -> out bf16 [N,K]. 64x64 tiles via LDS.
__global__ __launch_bounds__(256)
void transpose_w(const void* __restrict__ in, u16* __restrict__ out, int K, int N,
                 const int* __restrict__ flag) {
  __shared__ float t[64][65];
  const int tid = threadIdx.x;
  const int r = tid >> 4, c4 = tid & 15;
  const int n0 = blockIdx.x << 6, k0 = blockIdx.y << 6;
  const int fl = *flag;
#pragma unroll
  for (int i = 0; i < 4; ++i) {
    const int kk = r + i * 16;
    const size_t base = (size_t)(k0 + kk) * N + n0 + c4 * 4;
    if (fl) {
      const uint2 raw = *(const uint2*)((const u16*)in + base);
      t[kk][c4 * 4 + 0] = bf2f((u16)(raw.x & 0xFFFF));
      t[kk][c4 * 4 + 1] = bf2f((u16)(raw.x >> 16));
      t[kk][c4 * 4 + 2] = bf2f((u16)(raw.y & 0xFFFF));
      t[kk][c4 * 4 + 3] = bf2f((u16)(raw.y >> 16));
    } else {
      const float4 v = *(const float4*)((const float*)in + base);
      t[kk][c4 * 4 + 0] = v.x; t[kk][c4 * 4 + 1] = v.y;
      t[kk][c4 * 4 + 2] = v.z; t[kk][c4 * 4 + 3] = v.w;
    }
  }
  __syncthreads();
#pragma unroll
  for (int i = 0; i < 4; ++i) {
    const int nn = r + i * 16;
    uint2 ov;
    ov.x = (u32)f2bf(t[c4 * 4 + 0][nn]) | ((u32)f2bf(t[c4 * 4 + 1][nn]) << 16);
    ov.y = (u32)f2bf(t[c4 * 4 + 2][nn]) | ((u32)f2bf(t[c4 * 4 + 3][nn]) << 16);
    *(uint2*)&out[(size_t)(n0 + nn) * K + k0 + c4 * 4] = ov;
  }
}

// qkv bf16 [nb*2048, 3072] (V cols 2048..3071) -> vt [nb*16][d=64][s=2048]
// grid (16 h, 32 s-tiles, nb batches)
__global__ __launch_bounds__(256)
void transpose_v(const u16* __restrict__ qkv, u16* __restrict__ vt) {
  __shared__ __align__(16) u16 t[64][72];
  const int h = blockIdx.x, s0 = blockIdx.y << 6, b = blockIdx.z;
  const int tid = threadIdx.x;
  const int r = tid >> 2, g = tid & 3;
  const u16* src = &qkv[(size_t)(b * SEQ + s0 + r) * 3072 + 2048 + h * 64 + g * 16];
  *(u32x4a*)&t[r][g * 16]     = *(const u32x4a*)src;
  *(u32x4a*)&t[r][g * 16 + 8] = *(const u32x4a*)(src + 8);
  __syncthreads();
  union { u16 s[16]; u32x4 v[2]; } u;
#pragma unroll
  for (int e = 0; e < 16; ++e) u.s[e] = t[g * 16 + e][r];
  u16* dst = &vt[(size_t)((b * 16 + h) * 64 + r) * 2048 + s0 + g * 16];
  *(u32x4a*)dst = u.v[0];
  *(u32x4a*)(dst + 8) = u.v[1];
}

// ---------------- GEMM: C[M,N] = A[M,K]*BT[N,K]^T + bias ----------------
// 128x128 tile, BK=32, 4 waves 2x2. BF16_OUT picks store dtype.
template <bool BF16_OUT>
__global__ __launch_bounds__(256)
void gemm_bt(const u16* __restrict__ A, const u16* __restrict__ BT,
             const float* __restrict__ bias, void* __restrict__ Cv,
             int M, int N, int K) {
  constexpr int BK = 32, LDW = 40;
  __shared__ __align__(16) u16 lA[128 * LDW];
  __shared__ __align__(16) u16 lB[128 * LDW];
  const int tid = threadIdx.x;
  const int wid = tid >> 6, lane = tid & 63;
  const int quad = lane >> 4, l16 = lane & 15;
  const int tile_m = blockIdx.y << 7, tile_n = blockIdx.x << 7;
  const int wm = (wid >> 1) << 6, wn = (wid & 1) << 6;
  const int srow0 = tid >> 2, kc = (tid & 3) * 8;

  f32x4 acc[4][4] = {};

  for (int k0 = 0; k0 < K; k0 += BK) {
    u32x4 va[2], vb[2];
#pragma unroll
    for (int c = 0; c < 2; ++c) {
      const int row = srow0 + c * 64;
      va[c] = *(const u32x4a*)&A[(size_t)(tile_m + row) * K + k0 + kc];
      vb[c] = *(const u32x4a*)&BT[(size_t)(tile_n + row) * K + k0 + kc];
    }
    __syncthreads();
#pragma unroll
    for (int c = 0; c < 2; ++c) {
      const int row = srow0 + c * 64;
      *(u32x4a*)&lA[row * LDW + kc] = va[c];
      *(u32x4a*)&lB[row * LDW + kc] = vb[c];
    }
    __syncthreads();
    bf16x8 af[4], bfr[4];
#pragma unroll
    for (int i = 0; i < 4; ++i) {
      af[i]  = ld16(&lA[(wm + i * 16 + l16) * LDW + quad * 8]);
      bfr[i] = ld16(&lB[(wn + i * 16 + l16) * LDW + quad * 8]);
    }
#pragma unroll
    for (int i = 0; i < 4; ++i)
#pragma unroll
      for (int j = 0; j < 4; ++j) acc[i][j] = mfma16(af[i], bfr[j], acc[i][j]);
  }

#pragma unroll
  for (int j = 0; j < 4; ++j) {
    const int cg = tile_n + wn + j * 16 + l16;
    const float bv = bias[cg];
#pragma unroll
    for (int i = 0; i < 4; ++i) {
      const int rg = tile_m + wm + i * 16 + quad * 4;
#pragma unroll
      for (int r = 0; r < 4; ++r) {
        const float v = acc[i][j][r] + bv;
        if constexpr (BF16_OUT)
          ((u16*)Cv)[(size_t)(rg + r) * N + cg] = f2bf(v);
        else
          ((float*)Cv)[(size_t)(rg + r) * N + cg] = v;  // d_out is fp32
      }
    }
  }
}

// ---------------- causal flash attention ----------------
// grid (16 h, 32 qt, nb batches); wave w owns q rows qt*64+w*16..+15.
__global__ __launch_bounds__(256)
void attn_fwd(const u16* __restrict__ qkv, const u16* __restrict__ vt,
              u16* __restrict__ aout) {
  const int h = blockIdx.x, qt = blockIdx.y, b = blockIdx.z;
  const int tid = threadIdx.x, wid = tid >> 6, lane = tid & 63;
  const int quad = lane >> 4, l16 = lane & 15;
  const int q0 = qt * 64 + wid * 16;
  __shared__ __align__(16) u16 lP[4][16][72];  // per-wave, 144B row stride

  bf16x8 aq0, aq1;
  {
    const size_t qi = (size_t)(b * SEQ + q0 + l16) * 3072 + h * 64 + quad * 8;
    aq0 = ld16(&qkv[qi]);
    aq1 = ld16(&qkv[qi + 32]);
  }
  const f32x4 z = {0.f, 0.f, 0.f, 0.f};
  f32x4 o[4] = {z, z, z, z};
  float m_r[4] = {-1e30f, -1e30f, -1e30f, -1e30f};
  float l_r[4] = {0.f, 0.f, 0.f, 0.f};

  for (int kt = 0; kt <= qt; ++kt) {  // qt uniform per block: barriers legal
    const int kbase = kt * 64;
    f32x4 s[4];
#pragma unroll
    for (int f = 0; f < 4; ++f) {
      const size_t ki =
          (size_t)(b * SEQ + kbase + f * 16 + l16) * 3072 + 1024 + h * 64 + quad * 8;
      f32x4 a = z;
      a = mfma16(aq0, ld16(&qkv[ki]), a);
      a = mfma16(aq1, ld16(&qkv[ki + 32]), a);
      s[f] = a * 0.125f;  // 1/sqrt(64)
    }
    if (kt == qt) {  // diagonal: mask k_local > q_local
#pragma unroll
      for (int f = 0; f < 4; ++f)
#pragma unroll
        for (int r = 0; r < 4; ++r)
          if (f * 16 + l16 > wid * 16 + quad * 4 + r) s[f][r] = -1e30f;
    }
    float alpha[4];
#pragma unroll
    for (int r = 0; r < 4; ++r) {
      float mv = fmaxf(fmaxf(s[0][r], s[1][r]), fmaxf(s[2][r], s[3][r]));
      mv = fmaxf(mv, __shfl_xor(mv, 1));
      mv = fmaxf(mv, __shfl_xor(mv, 2));
      mv = fmaxf(mv, __shfl_xor(mv, 4));
      mv = fmaxf(mv, __shfl_xor(mv, 8));
      const float mn = fmaxf(m_r[r], mv);
      alpha[r] = __expf(m_r[r] - mn);
      m_r[r] = mn;
    }
    f32x4 p[4];
#pragma unroll
    for (int f = 0; f < 4; ++f)
#pragma unroll
      for (int r = 0; r < 4; ++r) p[f][r] = __expf(s[f][r] - m_r[r]);
#pragma unroll
    for (int r = 0; r < 4; ++r) {
      float sv = p[0][r] + p[1][r] + p[2][r] + p[3][r];
      sv += __shfl_xor(sv, 1);
      sv += __shfl_xor(sv, 2);
      sv += __shfl_xor(sv, 4);
      sv += __shfl_xor(sv, 8);
      l_r[r] = l_r[r] * alpha[r] + sv;
    }
#pragma unroll
    for (int f = 0; f < 4; ++f)
#pragma unroll
      for (int r = 0; r < 4; ++r) {
        o[f][r] *= alpha[r];
        lP[wid][quad * 4 + r][f * 16 + l16] = f2bf(p[f][r]);
      }
    __syncthreads();  // fence P writes -> reads
    const bf16x8 ap0 = ld16(&lP[wid][l16][quad * 8]);
    const bf16x8 ap1 = ld16(&lP[wid][l16][quad * 8 + 32]);
#pragma unroll
    for (int f = 0; f < 4; ++f) {
      const size_t vi =
          (size_t)((b * 16 + h) * 64 + f * 16 + l16) * 2048 + kbase + quad * 8;
      o[f] = mfma16(ap0, ld16(&vt[vi]), o[f]);
      o[f] = mfma16(ap1, ld16(&vt[vi + 32]), o[f]);
    }
    __syncthreads();  // P consumed before next iteration overwrites
  }
  float inv[4];
#pragma unroll
  for (int r = 0; r < 4; ++r) inv[r] = 1.0f / l_r[r];
#pragma unroll
  for (int f = 0; f < 4; ++f)
#pragma unroll
    for (int r = 0; r < 4; ++r)
      aout[(size_t)(b * SEQ + q0 + quad * 4 + r) * 1024 + h * 64 + f * 16 + l16] =
          f2bf(o[f][r] * inv[r]);
}

extern "C" void kernel_launch(void* const* d_in, const int* in_sizes, int n_in,
                              void* d_out, int out_size, void* d_ws, size_t ws_size,
                              hipStream_t stream) {
  const void* x     = d_in[0];
  const void* w_qkv = d_in[1];
  const void* b_qkv = d_in[2];
  const void* w_out = d_in[3];
  const void* b_out = d_in[4];
  float* out = (float*)d_out;  // reference output dtype is fp32

  // common prefix
  float* bqf   = (float*)d_ws;                      // [3072] fp32
  float* bof   = bqf + 3072;                        // [1024] fp32
  int*   flag  = (int*)(bof + 1024);                // [4]
  u16*   wqkvT = (u16*)(flag + 4);                  // [3072,1024]
  u16*   woutT = wqkvT + (size_t)3072 * 1024;       // [1024,1024]
  u16*   xb    = woutT + (size_t)1024 * 1024;       // [M,1024]

  detect_dtype<<<dim3(1), dim3(64), 0, stream>>>((const u16*)x, flag);
  cvt_bias<<<dim3(12), dim3(256), 0, stream>>>(b_qkv, bqf, 3072, flag);
  cvt_bias<<<dim3(4), dim3(256), 0, stream>>>(b_out, bof, 1024, flag);
  transpose_w<<<dim3(48, 16), dim3(256), 0, stream>>>(w_qkv, wqkvT, 1024, 3072, flag);
  transpose_w<<<dim3(16, 16), dim3(256), 0, stream>>>(w_out, woutT, 1024, 1024, flag);

  // full-batch path needs 92,291,088 B of ws; fall back to per-batch otherwise.
  const size_t FULL_WS = 92291088;  // constant across calls -> graph-safe branch
  if (ws_size >= FULL_WS) {
    u16* qkv = xb  + (size_t)8192 * 1024;           // [8192,3072]
    u16* vt  = qkv + (size_t)8192 * 3072;           // [64,64,2048]
    cvt_x<<<dim3(8192), dim3(256), 0, stream>>>(x, xb, flag, 0);
    gemm_bt<true ><<<dim3(24, 64), dim3(256), 0, stream>>>(xb, wqkvT, bqf, qkv,
                                                           8192, 3072, 1024);
    transpose_v<<<dim3(16, 32, 4), dim3(256), 0, stream>>>(qkv, vt);
    attn_fwd<<<dim3(16, 32, 4), dim3(256), 0, stream>>>(qkv, vt, xb);
    gemm_bt<false><<<dim3(8, 64), dim3(256), 0, stream>>>(xb, woutT, bof, out,
                                                          8192, 1024, 1024);
  } else {
    u16* qkvb = xb   + (size_t)2048 * 1024;         // [2048,3072]
    u16* vtb  = qkvb + (size_t)2048 * 3072;         // [16,64,2048]
    for (int b = 0; b < 4; ++b) {
      const size_t eoff4 = (size_t)b * 2048 * 1024 / 4;
      cvt_x<<<dim3(2048), dim3(256), 0, stream>>>(x, xb, flag, eoff4);
      gemm_bt<true ><<<dim3(24, 16), dim3(256), 0, stream>>>(xb, wqkvT, bqf, qkvb,
                                                             2048, 3072, 1024);
      transpose_v<<<dim3(16, 32, 1), dim3(256), 0, stream>>>(qkvb, vtb);
      attn_fwd<<<dim3(16, 32, 1), dim3(256), 0, stream>>>(qkvb, vtb, xb);
      gemm_bt<false><<<dim3(8, 16), dim3(256), 0, stream>>>(
          xb, woutT, bof, out + (size_t)b * 2048 * 1024, 2048, 1024, 1024);
    }
  }
}

// Round 9
// 544.307 us; speedup vs baseline: 1.5482x; 1.0854x over previous
//
#include <hip/hip_runtime.h>

typedef unsigned short u16;
typedef unsigned int u32;
using f32x4 = __attribute__((ext_vector_type(4))) float;
using u32x4 = __attribute__((ext_vector_type(4))) u32;
typedef u32x4 __attribute__((may_alias)) u32x4a;  // TBAA-safe 16B vector
using bf16x8 = __attribute__((ext_vector_type(8))) __bf16;

#define SEQ 2048  // per batch

// fp32 -> bf16 round-to-nearest-even
__device__ __forceinline__ u16 f2bf(float f) {
  union { float f; u32 u; } c; c.f = f;
  return (u16)((c.u + 0x7fffu + ((c.u >> 16) & 1u)) >> 16);
}
__device__ __forceinline__ float bf2f(u16 h) {
  union { u32 u; float f; } c; c.u = ((u32)h) << 16;
  return c.f;
}
__device__ __forceinline__ bf16x8 ld16(const u16* p) {
  return __builtin_bit_cast(bf16x8, *(const u32x4a*)p);
}
__device__ __forceinline__ f32x4 mfma16(bf16x8 a, bf16x8 b, f32x4 c) {
  return __builtin_amdgcn_mfma_f32_16x16x32_bf16(a, b, c, 0, 0, 0);
}
// async global->LDS, 16B/lane; LDS dest = wave-uniform base + lane*16
__device__ __forceinline__ void gload_lds16(const u16* g, u16* l) {
  __builtin_amdgcn_global_load_lds(
      (const __attribute__((address_space(1))) void*)g,
      (__attribute__((address_space(3))) void*)l, 16, 0, 0);
}

// ---------------- input dtype detection ----------------
__global__ void detect_dtype(const u16* __restrict__ x, int* __restrict__ flag) {
  if (threadIdx.x == 0) {
    int cnt = 0;
    for (int i = 0; i < 32; ++i) {
      const int e = (x[2 * i] >> 7) & 0xFF;
      cnt += (e >= 100 && e <= 140) ? 1 : 0;
    }
    *flag = (cnt >= 20) ? 1 : 0;  // 1 = inputs are bf16
  }
}

// ---------------- prep kernels ----------------

__global__ __launch_bounds__(256)
void cvt_x(const void* __restrict__ in, u16* __restrict__ out,
           const int* __restrict__ flag, size_t eoff4) {
  const size_t i = (size_t)blockIdx.x * 256 + threadIdx.x;
  if (*flag) {
    ((uint2*)out)[i] = ((const uint2*)in)[eoff4 + i];
  } else {
    const float4 v = ((const float4*)in)[eoff4 + i];
    uint2 ov;
    ov.x = (u32)f2bf(v.x) | ((u32)f2bf(v.y) << 16);
    ov.y = (u32)f2bf(v.z) | ((u32)f2bf(v.w) << 16);
    ((uint2*)out)[i] = ov;
  }
}

__global__ __launch_bounds__(256)
void cvt_bias(const void* __restrict__ in, float* __restrict__ out, int n,
              const int* __restrict__ flag) {
  const int i = blockIdx.x * 256 + threadIdx.x;
  if (i >= n) return;
  out[i] = (*flag) ? bf2f(((const u16*)in)[i]) : ((const float*)in)[i];
}

// in [K,N] (fp32 or bf16) -> out bf16 [N,K]. 64x64 tiles via LDS.
__global__ __launch_bounds__(256)
void transpose_w(const void* __restrict__ in, u16* __restrict__ out, int K, int N,
                 const int* __restrict__ flag) {
  __shared__ float t[64][65];
  const int tid = threadIdx.x;
  const int r = tid >> 4, c4 = tid & 15;
  const int n0 = blockIdx.x << 6, k0 = blockIdx.y << 6;
  const int fl = *flag;
#pragma unroll
  for (int i = 0; i < 4; ++i) {
    const int kk = r + i * 16;
    const size_t base = (size_t)(k0 + kk) * N + n0 + c4 * 4;
    if (fl) {
      const uint2 raw = *(const uint2*)((const u16*)in + base);
      t[kk][c4 * 4 + 0] = bf2f((u16)(raw.x & 0xFFFF));
      t[kk][c4 * 4 + 1] = bf2f((u16)(raw.x >> 16));
      t[kk][c4 * 4 + 2] = bf2f((u16)(raw.y & 0xFFFF));
      t[kk][c4 * 4 + 3] = bf2f((u16)(raw.y >> 16));
    } else {
      const float4 v = *(const float4*)((const float*)in + base);
      t[kk][c4 * 4 + 0] = v.x; t[kk][c4 * 4 + 1] = v.y;
      t[kk][c4 * 4 + 2] = v.z; t[kk][c4 * 4 + 3] = v.w;
    }
  }
  __syncthreads();
#pragma unroll
  for (int i = 0; i < 4; ++i) {
    const int nn = r + i * 16;
    uint2 ov;
    ov.x = (u32)f2bf(t[c4 * 4 + 0][nn]) | ((u32)f2bf(t[c4 * 4 + 1][nn]) << 16);
    ov.y = (u32)f2bf(t[c4 * 4 + 2][nn]) | ((u32)f2bf(t[c4 * 4 + 3][nn]) << 16);
    *(uint2*)&out[(size_t)(n0 + nn) * K + k0 + c4 * 4] = ov;
  }
}

// qkv bf16 [nb*2048, 3072] (V cols 2048..3071) -> vt [nb*16][d=64][s=2048]
__global__ __launch_bounds__(256)
void transpose_v(const u16* __restrict__ qkv, u16* __restrict__ vt) {
  __shared__ __align__(16) u16 t[64][72];
  const int h = blockIdx.x, s0 = blockIdx.y << 6, b = blockIdx.z;
  const int tid = threadIdx.x;
  const int r = tid >> 2, g = tid & 3;
  const u16* src = &qkv[(size_t)(b * SEQ + s0 + r) * 3072 + 2048 + h * 64 + g * 16];
  *(u32x4a*)&t[r][g * 16]     = *(const u32x4a*)src;
  *(u32x4a*)&t[r][g * 16 + 8] = *(const u32x4a*)(src + 8);
  __syncthreads();
  union { u16 s[16]; u32x4 v[2]; } u;
#pragma unroll
  for (int e = 0; e < 16; ++e) u.s[e] = t[g * 16 + e][r];
  u16* dst = &vt[(size_t)((b * 16 + h) * 64 + r) * 2048 + s0 + g * 16];
  *(u32x4a*)dst = u.v[0];
  *(u32x4a*)(dst + 8) = u.v[1];
}

// ---------------- GEMM: C[M,N] = A[M,K]*BT[N,K]^T + bias ----------------
// 128x128 tile, BK=32, 4 waves 2x2, m97-style global_load_lds staging:
// LDS row-major [128][32] u16; granule G = c*256 + wid*64 + lane maps to
// (row=G>>2, kcol=(G&3)*8); LDS dest = wave-uniform base + lane*16 (HW rule).
template <bool BF16_OUT>
__global__ __launch_bounds__(256)
void gemm_bt(const u16* __restrict__ A, const u16* __restrict__ BT,
             const float* __restrict__ bias, void* __restrict__ Cv,
             int M, int N, int K) {
  constexpr int BK = 32;
  __shared__ __align__(16) u16 lA[128 * BK];
  __shared__ __align__(16) u16 lB[128 * BK];
  const int tid = threadIdx.x;
  const int wid = tid >> 6, lane = tid & 63;
  const int quad = lane >> 4, l16 = lane & 15;
  const int tile_m = blockIdx.y << 7, tile_n = blockIdx.x << 7;
  const int wm = (wid >> 1) << 6, wn = (wid & 1) << 6;
  // staging geometry
  const int G0 = wid * 64 + lane, G1 = G0 + 256;
  const int r0 = G0 >> 2, c0 = (G0 & 3) * 8;
  const int r1 = G1 >> 2, c1 = (G1 & 3) * 8;
  u16* const dA0 = lA + wid * 512;         // (wid*64 granules)*8 u16
  u16* const dA1 = lA + 2048 + wid * 512;  // +256 granules
  u16* const dB0 = lB + wid * 512;
  u16* const dB1 = lB + 2048 + wid * 512;

  f32x4 acc[4][4] = {};

  for (int k0 = 0; k0 < K; k0 += BK) {
    __syncthreads();  // WAR: previous iteration's fragment reads complete
    gload_lds16(&A [(size_t)(tile_m + r0) * K + k0 + c0], dA0);
    gload_lds16(&BT[(size_t)(tile_n + r0) * K + k0 + c0], dB0);
    gload_lds16(&A [(size_t)(tile_m + r1) * K + k0 + c1], dA1);
    gload_lds16(&BT[(size_t)(tile_n + r1) * K + k0 + c1], dB1);
    __syncthreads();  // RAW: barrier drains vmcnt -> LDS tiles complete
    bf16x8 af[4], bfr[4];
#pragma unroll
    for (int i = 0; i < 4; ++i) {
      af[i]  = ld16(&lA[(wm + i * 16 + l16) * BK + quad * 8]);
      bfr[i] = ld16(&lB[(wn + i * 16 + l16) * BK + quad * 8]);
    }
#pragma unroll
    for (int i = 0; i < 4; ++i)
#pragma unroll
      for (int j = 0; j < 4; ++j) acc[i][j] = mfma16(af[i], bfr[j], acc[i][j]);
  }

#pragma unroll
  for (int j = 0; j < 4; ++j) {
    const int cg = tile_n + wn + j * 16 + l16;
    const float bv = bias[cg];
#pragma unroll
    for (int i = 0; i < 4; ++i) {
      const int rg = tile_m + wm + i * 16 + quad * 4;
#pragma unroll
      for (int r = 0; r < 4; ++r) {
        const float v = acc[i][j][r] + bv;
        if constexpr (BF16_OUT)
          ((u16*)Cv)[(size_t)(rg + r) * N + cg] = f2bf(v);
        else
          ((float*)Cv)[(size_t)(rg + r) * N + cg] = v;  // d_out is fp32
      }
    }
  }
}

// ---------------- causal flash attention ----------------
// grid (16 h, 32 qt-slots, nb batches); qt = 31 - blockIdx.y (LPT: heavy
// blocks dispatch first). Wave w owns q rows qt*64+w*16..+15.
// lP is wave-private ([wid] slice): no barriers — same-wave DS ordering is
// guaranteed (in-order DS pipe + compiler lgkmcnt on aliasing LDS accesses),
// so waves slip freely and the compiler can prefetch K across iterations.
__global__ __launch_bounds__(256)
void attn_fwd(const u16* __restrict__ qkv, const u16* __restrict__ vt,
              u16* __restrict__ aout) {
  const int h = blockIdx.x, qt = 31 - blockIdx.y, b = blockIdx.z;
  const int tid = threadIdx.x, wid = tid >> 6, lane = tid & 63;
  const int quad = lane >> 4, l16 = lane & 15;
  const int q0 = qt * 64 + wid * 16;
  __shared__ __align__(16) u16 lP[4][16][72];  // per-wave, 144B row stride

  bf16x8 aq0, aq1;
  {
    const size_t qi = (size_t)(b * SEQ + q0 + l16) * 3072 + h * 64 + quad * 8;
    aq0 = ld16(&qkv[qi]);
    aq1 = ld16(&qkv[qi + 32]);
  }
  const f32x4 z = {0.f, 0.f, 0.f, 0.f};
  f32x4 o[4] = {z, z, z, z};
  float m_r[4] = {-1e30f, -1e30f, -1e30f, -1e30f};
  float l_r[4] = {0.f, 0.f, 0.f, 0.f};

  for (int kt = 0; kt <= qt; ++kt) {
    const int kbase = kt * 64;
    f32x4 s[4];
#pragma unroll
    for (int f = 0; f < 4; ++f) {
      const size_t ki =
          (size_t)(b * SEQ + kbase + f * 16 + l16) * 3072 + 1024 + h * 64 + quad * 8;
      f32x4 a = z;
      a = mfma16(aq0, ld16(&qkv[ki]), a);
      a = mfma16(aq1, ld16(&qkv[ki + 32]), a);
      s[f] = a * 0.125f;  // 1/sqrt(64)
    }
    // V fragments issued early: no dependency on softmax -> latency hides
    // under the shuffle chains below.
    bf16x8 vf0[4], vf1[4];
#pragma unroll
    for (int f = 0; f < 4; ++f) {
      const size_t vi =
          (size_t)((b * 16 + h) * 64 + f * 16 + l16) * 2048 + kbase + quad * 8;
      vf0[f] = ld16(&vt[vi]);
      vf1[f] = ld16(&vt[vi + 32]);
    }
    if (kt == qt) {  // diagonal: mask k_local > q_local
#pragma unroll
      for (int f = 0; f < 4; ++f)
#pragma unroll
        for (int r = 0; r < 4; ++r)
          if (f * 16 + l16 > wid * 16 + quad * 4 + r) s[f][r] = -1e30f;
    }
    float alpha[4];
#pragma unroll
    for (int r = 0; r < 4; ++r) {
      float mv = fmaxf(fmaxf(s[0][r], s[1][r]), fmaxf(s[2][r], s[3][r]));
      mv = fmaxf(mv, __shfl_xor(mv, 1));
      mv = fmaxf(mv, __shfl_xor(mv, 2));
      mv = fmaxf(mv, __shfl_xor(mv, 4));
      mv = fmaxf(mv, __shfl_xor(mv, 8));
      const float mn = fmaxf(m_r[r], mv);
      alpha[r] = __expf(m_r[r] - mn);
      m_r[r] = mn;
    }
    f32x4 p[4];
#pragma unroll
    for (int f = 0; f < 4; ++f)
#pragma unroll
      for (int r = 0; r < 4; ++r) p[f][r] = __expf(s[f][r] - m_r[r]);
#pragma unroll
    for (int r = 0; r < 4; ++r) {
      float sv = p[0][r] + p[1][r] + p[2][r] + p[3][r];
      sv += __shfl_xor(sv, 1);
      sv += __shfl_xor(sv, 2);
      sv += __shfl_xor(sv, 4);
      sv += __shfl_xor(sv, 8);
      l_r[r] = l_r[r] * alpha[r] + sv;
    }
#pragma unroll
    for (int f = 0; f < 4; ++f)
#pragma unroll
      for (int r = 0; r < 4; ++r) {
        o[f][r] *= alpha[r];
        lP[wid][quad * 4 + r][f * 16 + l16] = f2bf(p[f][r]);
      }
    const bf16x8 ap0 = ld16(&lP[wid][l16][quad * 8]);
    const bf16x8 ap1 = ld16(&lP[wid][l16][quad * 8 + 32]);
#pragma unroll
    for (int f = 0; f < 4; ++f) {
      o[f] = mfma16(ap0, vf0[f], o[f]);
      o[f] = mfma16(ap1, vf1[f], o[f]);
    }
  }
  float inv[4];
#pragma unroll
  for (int r = 0; r < 4; ++r) inv[r] = 1.0f / l_r[r];
#pragma unroll
  for (int f = 0; f < 4; ++f)
#pragma unroll
    for (int r = 0; r < 4; ++r)
      aout[(size_t)(b * SEQ + q0 + quad * 4 + r) * 1024 + h * 64 + f * 16 + l16] =
          f2bf(o[f][r] * inv[r]);
}

extern "C" void kernel_launch(void* const* d_in, const int* in_sizes, int n_in,
                              void* d_out, int out_size, void* d_ws, size_t ws_size,
                              hipStream_t stream) {
  const void* x     = d_in[0];
  const void* w_qkv = d_in[1];
  const void* b_qkv = d_in[2];
  const void* w_out = d_in[3];
  const void* b_out = d_in[4];
  float* out = (float*)d_out;  // reference output dtype is fp32

  // common prefix
  float* bqf   = (float*)d_ws;                      // [3072] fp32
  float* bof   = bqf + 3072;                        // [1024] fp32
  int*   flag  = (int*)(bof + 1024);                // [4]
  u16*   wqkvT = (u16*)(flag + 4);                  // [3072,1024]
  u16*   woutT = wqkvT + (size_t)3072 * 1024;       // [1024,1024]
  u16*   xb    = woutT + (size_t)1024 * 1024;       // [M,1024]

  detect_dtype<<<dim3(1), dim3(64), 0, stream>>>((const u16*)x, flag);
  cvt_bias<<<dim3(12), dim3(256), 0, stream>>>(b_qkv, bqf, 3072, flag);
  cvt_bias<<<dim3(4), dim3(256), 0, stream>>>(b_out, bof, 1024, flag);
  transpose_w<<<dim3(48, 16), dim3(256), 0, stream>>>(w_qkv, wqkvT, 1024, 3072, flag);
  transpose_w<<<dim3(16, 16), dim3(256), 0, stream>>>(w_out, woutT, 1024, 1024, flag);

  // full-batch path needs 92,291,088 B of ws; fall back to per-batch otherwise.
  const size_t FULL_WS = 92291088;  // constant across calls -> graph-safe branch
  if (ws_size >= FULL_WS) {
    u16* qkv = xb  + (size_t)8192 * 1024;           // [8192,3072]
    u16* vt  = qkv + (size_t)8192 * 3072;           // [64,64,2048]
    cvt_x<<<dim3(8192), dim3(256), 0, stream>>>(x, xb, flag, 0);
    gemm_bt<true ><<<dim3(24, 64), dim3(256), 0, stream>>>(xb, wqkvT, bqf, qkv,
                                                           8192, 3072, 1024);
    transpose_v<<<dim3(16, 32, 4), dim3(256), 0, stream>>>(qkv, vt);
    attn_fwd<<<dim3(16, 32, 4), dim3(256), 0, stream>>>(qkv, vt, xb);
    gemm_bt<false><<<dim3(8, 64), dim3(256), 0, stream>>>(xb, woutT, bof, out,
                                                          8192, 1024, 1024);
  } else {
    u16* qkvb = xb   + (size_t)2048 * 1024;         // [2048,3072]
    u16* vtb  = qkvb + (size_t)2048 * 3072;         // [16,64,2048]
    for (int b = 0; b < 4; ++b) {
      const size_t eoff4 = (size_t)b * 2048 * 1024 / 4;
      cvt_x<<<dim3(2048), dim3(256), 0, stream>>>(x, xb, flag, eoff4);
      gemm_bt<true ><<<dim3(24, 16), dim3(256), 0, stream>>>(xb, wqkvT, bqf, qkvb,
                                                             2048, 3072, 1024);
      transpose_v<<<dim3(16, 32, 1), dim3(256), 0, stream>>>(qkvb, vtb);
      attn_fwd<<<dim3(16, 32, 1), dim3(256), 0, stream>>>(qkvb, vtb, xb);
      gemm_bt<false><<<dim3(8, 16), dim3(256), 0, stream>>>(
          xb, woutT, bof, out + (size_t)b * 2048 * 1024, 2048, 1024, 1024);
    }
  }
}